// Round 3
// baseline (262.190 us; speedup 1.0000x reference)
//
#include <hip/hip_runtime.h>
#include <stdint.h>

// ============================================================================
// Fused 2-layer tanh RNN (batch_first, eval) + linear head, MI355X gfx950.
//
// Design (round 3 == round 2, resubmitted after infra failures):
//  - ONE persistent kernel: 256 blocks x 256 threads (4 waves). Block owns 16
//    batch rows for all T=64 steps (rows independent across blocks).
//  - All matmuls via v_mfma_f32_16x16x32_bf16 with hi/lo bf16 split of fp32
//    operands (keep AhBh + AhBl + AlBh; error ~1e-5 rel => fp32-class).
//  - Wave w computes output cols [16w,16w+16) of every product.
//  - x[16 rows][124] staged per step into LDS pre-split to bf16 hi/lo;
//    global loads issued 2 steps ahead (HBM latency hidden under compute).
//  - h0,h1 in LDS as bf16 hi/lo ping-pong; 2 barriers/step.
//  - Accumulator splitting (dependent-MFMA chains <= 4) and hoisting of
//    h1_prev@Whh1^T into phase A (needs only pre-barrier state) so the
//    post-barrier tail is 6 MFMAs. At 1 wave/SIMD chains are exposed.
//  - FC head folded into the tail. d_ws unused.
//
// Fragment layouts (A/B: m92-ladder-consistent; D: m89-verified):
//   A (16Mx32K): row = lane&15, k = 8*(lane>>4) + j   (j = 0..7 contiguous)
//   B (32Kx16N): col = lane&15, k = 8*(lane>>4) + j
//   D (16x16)  : col = lane&15, row = 4*(lane>>4) + reg
// Note: k-order errors cancel (same bijection applied to A and B frags);
// only row/col = lane&15 and the m89 D layout are load-bearing.
// ============================================================================

typedef float  f32x4 __attribute__((ext_vector_type(4)));
typedef short  s16x8 __attribute__((ext_vector_type(8)));
typedef unsigned int u32;
typedef unsigned int u32x4 __attribute__((ext_vector_type(4)));

#define TSTEPS 64
#define FIN    124
#define HID    64

__device__ __forceinline__ f32x4 zero4() {
  f32x4 z = {0.f, 0.f, 0.f, 0.f};
  return z;
}

// Split 8 consecutive fp32 (two f32x4, k ascending) into hi/lo bf16x8 frags.
// hi = truncation (exact upper bits), lo = truncate(v - hi).
__device__ __forceinline__ void split8(const f32x4 a, const f32x4 b,
                                       s16x8& hi, s16x8& lo) {
  float e[8] = {a[0], a[1], a[2], a[3], b[0], b[1], b[2], b[3]};
  u32x4 hu, lu;
#pragma unroll
  for (int p = 0; p < 4; ++p) {
    u32 u0 = __float_as_uint(e[2 * p]);
    u32 u1 = __float_as_uint(e[2 * p + 1]);
    u32 h0b = u0 & 0xFFFF0000u;
    u32 h1b = u1 & 0xFFFF0000u;
    hu[p] = (u0 >> 16) | h1b;
    float r0 = e[2 * p]     - __uint_as_float(h0b);
    float r1 = e[2 * p + 1] - __uint_as_float(h1b);
    lu[p] = (__float_as_uint(r0) >> 16) | (__float_as_uint(r1) & 0xFFFF0000u);
  }
  hi = __builtin_bit_cast(s16x8, hu);
  lo = __builtin_bit_cast(s16x8, lu);
}

__device__ __forceinline__ f32x4 MFMA(s16x8 a, s16x8 b, f32x4 c) {
  return __builtin_amdgcn_mfma_f32_16x16x32_bf16(a, b, c, 0, 0, 0);
}

__device__ __forceinline__ float tanh_f(float x) {
  x = fminf(15.f, fmaxf(-15.f, x));
  float e = __builtin_amdgcn_exp2f(x * 2.88539008177793f); // e^{2x}
  return (e - 1.f) * __builtin_amdgcn_rcpf(e + 1.f);
}

__global__ __launch_bounds__(256, 1) void rnn2_fused_kernel(
    const float* __restrict__ x,
    const float* __restrict__ Wih0, const float* __restrict__ Whh0,
    const float* __restrict__ bih0, const float* __restrict__ bhh0,
    const float* __restrict__ Wih1, const float* __restrict__ Whh1,
    const float* __restrict__ bih1, const float* __restrict__ bhh1,
    const float* __restrict__ Wfc,  const float* __restrict__ bfc,
    float* __restrict__ out) {
  // x tile buffers (bf16 hi/lo), padded stride 136 halves (272 B).
  __shared__ __align__(16) unsigned short XH[2][16][136];
  __shared__ __align__(16) unsigned short XL[2][16][136];
  // state buffers (bf16 hi/lo), padded stride 72 halves (144 B).
  __shared__ __align__(16) unsigned short S0H[2][16][72];
  __shared__ __align__(16) unsigned short S0L[2][16][72];
  __shared__ __align__(16) unsigned short S1H[2][16][72];
  __shared__ __align__(16) unsigned short S1L[2][16][72];
  __shared__ float WFC[64];
  __shared__ float RED[64];

  const int tid  = (int)threadIdx.x;
  const int lane = tid & 63;
  const int wv   = tid >> 6;       // wave id 0..3 -> output col slice
  const int r16  = lane & 15;      // A row / B,D col within tile
  const int g    = lane >> 4;      // k-block (A/B) / row-block (D)
  const int col  = 16 * wv + r16;  // global output col this lane owns
  const int n0   = (int)blockIdx.x * 16;

  // ---- weight fragments (pre-split, register-resident) ----
  // B[k][col] = W[col][k]: 8 consecutive k from row `col` of W.
  s16x8 WH[3][2][2];  // [0=Whh0 1=Wih1 2=Whh1][K-chunk c][0=hi 1=lo]
  {
    const float* Wp[3] = {Whh0, Wih1, Whh1};
#pragma unroll
    for (int p = 0; p < 3; ++p) {
#pragma unroll
      for (int c = 0; c < 2; ++c) {
        const float* base = Wp[p] + col * HID + 32 * c + 8 * g;
        f32x4 a = *(const f32x4*)base;
        f32x4 b = *(const f32x4*)(base + 4);
        split8(a, b, WH[p][c][0], WH[p][c][1]);
      }
    }
  }
  s16x8 WI[4][2];  // W_ih0 [K-chunk 0..3][hi/lo], K padded 124 -> 128
#pragma unroll
  for (int c = 0; c < 4; ++c) {
    const float* base = Wih0 + col * FIN + 32 * c + 8 * g;
    f32x4 a = *(const f32x4*)base;  // k = 32c+8g .. +3 always < 124
    f32x4 b = zero4();
    if (!(c == 3 && g == 3)) b = *(const f32x4*)(base + 4);  // mask k>=124
    split8(a, b, WI[c][0], WI[c][1]);
  }

  const float bias0 = bih0[col] + bhh0[col];
  const float bias1 = bih1[col] + bhh1[col];

  // ---- zero initial state (ping buffer 0) + stage FC weights ----
  {
    u32* z0 = (u32*)&S0H[0][0][0];
    u32* z1 = (u32*)&S0L[0][0][0];
    u32* z2 = (u32*)&S1H[0][0][0];
    u32* z3 = (u32*)&S1L[0][0][0];
    for (int i = tid; i < 16 * 72 / 2; i += 256) {
      z0[i] = 0; z1[i] = 0; z2[i] = 0; z3[i] = 0;
    }
  }
  if (tid < 64) WFC[tid] = Wfc[tid];

  // ---- x staging: thread (xr, xs) owns 8 consecutive k of one row ----
  const int xr = tid >> 4;  // row 0..15
  const int xs = tid & 15;  // k-octet 0..15 (xs==15 covers k=120..127, pad)
  const float* xrow = x + (size_t)(n0 + xr) * (TSTEPS * FIN);
  f32x4 xa, xb;
  {  // t = 0: load + stage into buffer 0
    const float* b0 = xrow + 8 * xs;
    xa = *(const f32x4*)b0;
    xb = zero4();
    if (xs != 15) xb = *(const f32x4*)(b0 + 4);
    s16x8 fh, fl;
    split8(xa, xb, fh, fl);
    *(s16x8*)&XH[0][xr][8 * xs] = fh;
    *(s16x8*)&XL[0][xr][8 * xs] = fl;
  }
  {  // t = 1 into regs
    const float* b1 = xrow + FIN + 8 * xs;
    xa = *(const f32x4*)b1;
    xb = zero4();
    if (xs != 15) xb = *(const f32x4*)(b1 + 4);
  }
  __syncthreads();

  // ---- time loop: 2 barriers / step ----
#pragma unroll 2
  for (int t = 0; t < TSTEPS; ++t) {
    const int P = t & 1;

    // 1) stage x_{t+1} (regs -> LDS buffer 1-P); consumed next step.
    {
      s16x8 fh, fl;
      split8(xa, xb, fh, fl);
      *(s16x8*)&XH[1 - P][xr][8 * xs] = fh;
      *(s16x8*)&XL[1 - P][xr][8 * xs] = fl;
    }
    // 2) issue x_{t+2} loads (HBM latency hidden under this whole step).
    {
      int t2 = (t + 2 < TSTEPS) ? (t + 2) : (TSTEPS - 1);
      const float* bp = xrow + t2 * FIN + 8 * xs;
      xa = *(const f32x4*)bp;
      xb = zero4();
      if (xs != 15) xb = *(const f32x4*)(bp + 4);
    }

    // 3) Load all pre-barrier A-fragments (h0 prev, x cur, h1 prev).
    s16x8 h0h[2], h0l[2], xh[4], xl[4], h1h[2], h1l[2];
#pragma unroll
    for (int c = 0; c < 2; ++c) {
      h0h[c] = *(const s16x8*)&S0H[P][r16][32 * c + 8 * g];
      h0l[c] = *(const s16x8*)&S0L[P][r16][32 * c + 8 * g];
      h1h[c] = *(const s16x8*)&S1H[P][r16][32 * c + 8 * g];
      h1l[c] = *(const s16x8*)&S1L[P][r16][32 * c + 8 * g];
    }
#pragma unroll
    for (int c = 0; c < 4; ++c) {
      xh[c] = *(const s16x8*)&XH[P][r16][32 * c + 8 * g];
      xl[c] = *(const s16x8*)&XL[P][r16][32 * c + 8 * g];
    }

    // 4) Phase A MFMAs + hoisted h1_prev@Whh1^T. Six short chains (<=4),
    //    interleaved round-robin so no back-to-back dependent MFMAs.
    f32x4 a0 = {bias0, bias0, bias0, bias0};      // hh AhBh + x AhBh c01
    f32x4 a1 = zero4();                           // hh AhBl + x AhBl c01
    f32x4 a2 = zero4();                           // hh AlBh + x AlBh c01
    f32x4 a3 = zero4();                           // x AhBh c23
    f32x4 a4 = zero4();                           // x AhBl c23
    f32x4 a5 = zero4();                           // x AlBh c23
    f32x4 b0 = {bias1, bias1, bias1, bias1};      // h1 AhBh + AhBl (hoisted)
    f32x4 b1 = zero4();                           // h1 AlBh       (hoisted)

    a0 = MFMA(h0h[0], WH[0][0][0], a0);
    a1 = MFMA(h0h[0], WH[0][0][1], a1);
    a2 = MFMA(h0l[0], WH[0][0][0], a2);
    a3 = MFMA(xh[2], WI[2][0], a3);
    a4 = MFMA(xh[2], WI[2][1], a4);
    a5 = MFMA(xl[2], WI[2][0], a5);
    b0 = MFMA(h1h[0], WH[2][0][0], b0);
    b1 = MFMA(h1l[0], WH[2][0][0], b1);

    a0 = MFMA(h0h[1], WH[0][1][0], a0);
    a1 = MFMA(h0h[1], WH[0][1][1], a1);
    a2 = MFMA(h0l[1], WH[0][1][0], a2);
    a3 = MFMA(xh[3], WI[3][0], a3);
    a4 = MFMA(xh[3], WI[3][1], a4);
    a5 = MFMA(xl[3], WI[3][0], a5);
    b0 = MFMA(h1h[1], WH[2][1][0], b0);
    b1 = MFMA(h1l[1], WH[2][1][0], b1);

    a0 = MFMA(xh[0], WI[0][0], a0);
    a1 = MFMA(xh[0], WI[0][1], a1);
    a2 = MFMA(xl[0], WI[0][0], a2);
    b0 = MFMA(h1h[0], WH[2][0][1], b0);

    a0 = MFMA(xh[1], WI[1][0], a0);
    a1 = MFMA(xh[1], WI[1][1], a1);
    a2 = MFMA(xl[1], WI[1][0], a2);
    b0 = MFMA(h1h[1], WH[2][1][1], b0);

    // 5) h0_new = tanh(sum), write to S0[1-P] (D: row = 4g+i, col = col).
#pragma unroll
    for (int i = 0; i < 4; ++i) {
      float h = tanh_f(((a0[i] + a1[i]) + (a2[i] + a3[i])) + (a4[i] + a5[i]));
      u32 u  = __float_as_uint(h);
      u32 hb = u & 0xFFFF0000u;
      S0H[1 - P][4 * g + i][col] = (unsigned short)(u >> 16);
      float rl = h - __uint_as_float(hb);
      S0L[1 - P][4 * g + i][col] = (unsigned short)(__float_as_uint(rl) >> 16);
    }
    __syncthreads();

    // 6) Phase B tail: h0_new @ Wih1^T only (6 MFMAs, chains <= 4).
    f32x4 b2 = zero4();
    f32x4 b3 = zero4();
#pragma unroll
    for (int c = 0; c < 2; ++c) {
      s16x8 ah = *(const s16x8*)&S0H[1 - P][r16][32 * c + 8 * g];
      s16x8 al = *(const s16x8*)&S0L[1 - P][r16][32 * c + 8 * g];
      b2 = MFMA(ah, WH[1][c][0], b2);
      b3 = MFMA(al, WH[1][c][0], b3);
      b2 = MFMA(ah, WH[1][c][1], b2);
    }
#pragma unroll
    for (int i = 0; i < 4; ++i) {
      float h = tanh_f((b0[i] + b1[i]) + (b2[i] + b3[i]));
      u32 u  = __float_as_uint(h);
      u32 hb = u & 0xFFFF0000u;
      S1H[1 - P][4 * g + i][col] = (unsigned short)(u >> 16);
      float rl = h - __uint_as_float(hb);
      S1L[1 - P][4 * g + i][col] = (unsigned short)(__float_as_uint(rl) >> 16);
    }
    __syncthreads();
  }

  // ---- FC head: out[n] = h1[n] . Wfc + bfc. Final h1 in buffer 0
  // (t=63: P=1, wrote 1-P=0). Last __syncthreads already executed.
  if (tid < 64) {
    const int r = tid & 15;
    const int q = tid >> 4;
    float acc = 0.f;
#pragma unroll
    for (int k = 0; k < 16; ++k) {
      int kk = 16 * q + k;
      float hv = __uint_as_float(((u32)S1H[0][r][kk]) << 16) +
                 __uint_as_float(((u32)S1L[0][r][kk]) << 16);
      acc += hv * WFC[kk];
    }
    RED[tid] = acc;
  }
  __syncthreads();
  if (tid < 16) {
    float o = RED[tid] + RED[tid + 16] + RED[tid + 32] + RED[tid + 48] + bfc[0];
    out[n0 + tid] = o;
  }
}

extern "C" void kernel_launch(void* const* d_in, const int* in_sizes, int n_in,
                              void* d_out, int out_size, void* d_ws,
                              size_t ws_size, hipStream_t stream) {
  (void)in_sizes; (void)n_in; (void)d_ws; (void)ws_size; (void)out_size;
  const float* x    = (const float*)d_in[0];
  const float* Wih0 = (const float*)d_in[1];
  const float* Whh0 = (const float*)d_in[2];
  const float* bih0 = (const float*)d_in[3];
  const float* bhh0 = (const float*)d_in[4];
  const float* Wih1 = (const float*)d_in[5];
  const float* Whh1 = (const float*)d_in[6];
  const float* bih1 = (const float*)d_in[7];
  const float* bhh1 = (const float*)d_in[8];
  const float* Wfc  = (const float*)d_in[9];
  const float* bfc  = (const float*)d_in[10];

  rnn2_fused_kernel<<<256, 256, 0, stream>>>(
      x, Wih0, Whh0, bih0, bhh0, Wih1, Whh1, bih1, bhh1, Wfc, bfc,
      (float*)d_out);
}

// Round 4
// 222.445 us; speedup vs baseline: 1.1787x; 1.1787x over previous
//
#include <hip/hip_runtime.h>
#include <hip/hip_bf16.h>
#include <stdint.h>

// ============================================================================
// Fused 2-layer tanh RNN (batch_first, eval) + linear head, MI355X gfx950.
//
// Round 4 changes (baseline 117.6 us, latency-bound: MfmaUtil 10.7%,
// VALUBusy 20.8%, Occupancy 11%):
//  1. lgkmcnt-only barriers (asm s_waitcnt lgkmcnt(0) + s_barrier) instead of
//     __syncthreads: __syncthreads drains vmcnt(0), serializing the 2-step-
//     ahead x prefetch into every barrier (~300-900 cyc/step). All cross-wave
//     traffic is LDS, so lgkmcnt(0) suffices; the compiler still inserts the
//     vmcnt wait at the xa/xb register use (one full step after issue => ~0).
//  2. Cheaper tanh: 1 - 2*rcp(exp2(k*x)+1), 5 VALU ops, no clamp needed
//     (e=inf => 1, e=0 => -1; NaN impossible from bounded MFMA sums).
//  3. RNE hi/lo splits via __float2bfloat16 (same op count as bit-twiddled
//     truncation, half the |lo| => better absmax margin).
// Unchanged: 256 blocks x 4 waves, 16 rows/block, per-wave 16-col tile,
// mfma_f32_16x16x32_bf16 three-term hi/lo GEMMs, LDS ping-pong state,
// 2 barriers/step, accumulator chains <= 4, h1@Whh1 hoisted into phase A.
//
// Fragment layouts (A/B: m92-ladder-consistent; D: m89-verified):
//   A (16Mx32K): row = lane&15, k = 8*(lane>>4) + j
//   B (32Kx16N): col = lane&15, k = 8*(lane>>4) + j
//   D (16x16)  : col = lane&15, row = 4*(lane>>4) + reg
// k-order errors cancel (same bijection on A and B frags).
// ============================================================================

typedef float  f32x4 __attribute__((ext_vector_type(4)));
typedef short  s16x8 __attribute__((ext_vector_type(8)));
typedef unsigned int u32;

#define TSTEPS 64
#define FIN    124
#define HID    64

__device__ __forceinline__ f32x4 zero4() {
  f32x4 z = {0.f, 0.f, 0.f, 0.f};
  return z;
}

// Barrier with LDS-only drain: does NOT wait vmcnt, so global prefetch loads
// stay in flight across it (T4 pattern; __syncthreads would drain vmcnt(0)).
__device__ __forceinline__ void barrier_lds() {
  asm volatile("s_waitcnt lgkmcnt(0)" ::: "memory");
  __builtin_amdgcn_s_barrier();
  asm volatile("" ::: "memory");
}

// RNE split of 8 consecutive fp32 into hi/lo bf16x8 (v = hi + lo + O(2^-18)).
__device__ __forceinline__ void split8(const f32x4 a, const f32x4 b,
                                       s16x8& hi, s16x8& lo) {
  float e[8] = {a[0], a[1], a[2], a[3], b[0], b[1], b[2], b[3]};
  s16x8 h, l;
#pragma unroll
  for (int p = 0; p < 8; ++p) {
    float v = e[p];
    __hip_bfloat16 bh = __float2bfloat16(v);           // RNE
    float r = v - __bfloat162float(bh);
    __hip_bfloat16 bl = __float2bfloat16(r);
    h[p] = (short)__builtin_bit_cast(unsigned short, bh);
    l[p] = (short)__builtin_bit_cast(unsigned short, bl);
  }
  hi = h;
  lo = l;
}

__device__ __forceinline__ f32x4 MFMA(s16x8 a, s16x8 b, f32x4 c) {
  return __builtin_amdgcn_mfma_f32_16x16x32_bf16(a, b, c, 0, 0, 0);
}

// tanh(x) = 1 - 2/(e^{2x}+1); e^{2x} = exp2(x * 2/ln2). Inf-safe unclamped.
__device__ __forceinline__ float tanh_f(float x) {
  float e = __builtin_amdgcn_exp2f(x * 2.885390081777927f);
  return __builtin_fmaf(-2.f, __builtin_amdgcn_rcpf(e + 1.f), 1.f);
}

__global__ __launch_bounds__(256, 1) void rnn2_fused_kernel(
    const float* __restrict__ x,
    const float* __restrict__ Wih0, const float* __restrict__ Whh0,
    const float* __restrict__ bih0, const float* __restrict__ bhh0,
    const float* __restrict__ Wih1, const float* __restrict__ Whh1,
    const float* __restrict__ bih1, const float* __restrict__ bhh1,
    const float* __restrict__ Wfc,  const float* __restrict__ bfc,
    float* __restrict__ out) {
  __shared__ __align__(16) unsigned short XH[2][16][136];
  __shared__ __align__(16) unsigned short XL[2][16][136];
  __shared__ __align__(16) unsigned short S0H[2][16][72];
  __shared__ __align__(16) unsigned short S0L[2][16][72];
  __shared__ __align__(16) unsigned short S1H[2][16][72];
  __shared__ __align__(16) unsigned short S1L[2][16][72];
  __shared__ float WFC[64];
  __shared__ float RED[64];

  const int tid  = (int)threadIdx.x;
  const int lane = tid & 63;
  const int wv   = tid >> 6;
  const int r16  = lane & 15;
  const int g    = lane >> 4;
  const int col  = 16 * wv + r16;
  const int n0   = (int)blockIdx.x * 16;

  // ---- weight fragments (pre-split, register-resident) ----
  s16x8 WH[3][2][2];  // [0=Whh0 1=Wih1 2=Whh1][K-chunk][0=hi 1=lo]
  {
    const float* Wp[3] = {Whh0, Wih1, Whh1};
#pragma unroll
    for (int p = 0; p < 3; ++p) {
#pragma unroll
      for (int c = 0; c < 2; ++c) {
        const float* base = Wp[p] + col * HID + 32 * c + 8 * g;
        f32x4 a = *(const f32x4*)base;
        f32x4 b = *(const f32x4*)(base + 4);
        split8(a, b, WH[p][c][0], WH[p][c][1]);
      }
    }
  }
  s16x8 WI[4][2];  // W_ih0, K padded 124 -> 128
#pragma unroll
  for (int c = 0; c < 4; ++c) {
    const float* base = Wih0 + col * FIN + 32 * c + 8 * g;
    f32x4 a = *(const f32x4*)base;
    f32x4 b = zero4();
    if (!(c == 3 && g == 3)) b = *(const f32x4*)(base + 4);
    split8(a, b, WI[c][0], WI[c][1]);
  }

  const float bias0 = bih0[col] + bhh0[col];
  const float bias1 = bih1[col] + bhh1[col];

  // ---- zero initial state (ping buffer 0) + stage FC weights ----
  {
    u32* z0 = (u32*)&S0H[0][0][0];
    u32* z1 = (u32*)&S0L[0][0][0];
    u32* z2 = (u32*)&S1H[0][0][0];
    u32* z3 = (u32*)&S1L[0][0][0];
    for (int i = tid; i < 16 * 72 / 2; i += 256) {
      z0[i] = 0; z1[i] = 0; z2[i] = 0; z3[i] = 0;
    }
  }
  if (tid < 64) WFC[tid] = Wfc[tid];

  // ---- x staging: thread (xr, xs) owns 8 consecutive k of one row ----
  const int xr = tid >> 4;
  const int xs = tid & 15;
  const float* xrow = x + (size_t)(n0 + xr) * (TSTEPS * FIN);
  f32x4 xa, xb;
  {  // t = 0: load + stage into buffer 0
    const float* b0 = xrow + 8 * xs;
    xa = *(const f32x4*)b0;
    xb = zero4();
    if (xs != 15) xb = *(const f32x4*)(b0 + 4);
    s16x8 fh, fl;
    split8(xa, xb, fh, fl);
    *(s16x8*)&XH[0][xr][8 * xs] = fh;
    *(s16x8*)&XL[0][xr][8 * xs] = fl;
  }
  {  // t = 1 into regs
    const float* b1 = xrow + FIN + 8 * xs;
    xa = *(const f32x4*)b1;
    xb = zero4();
    if (xs != 15) xb = *(const f32x4*)(b1 + 4);
  }
  barrier_lds();

  // ---- time loop: 2 LDS-only barriers / step ----
#pragma unroll 2
  for (int t = 0; t < TSTEPS; ++t) {
    const int P = t & 1;

    // 1) stage x_{t+1} (regs -> LDS buffer 1-P); consumed next step.
    {
      s16x8 fh, fl;
      split8(xa, xb, fh, fl);
      *(s16x8*)&XH[1 - P][xr][8 * xs] = fh;
      *(s16x8*)&XL[1 - P][xr][8 * xs] = fl;
    }
    // 2) issue x_{t+2} loads; they stay in flight across both barriers now.
    {
      int t2 = (t + 2 < TSTEPS) ? (t + 2) : (TSTEPS - 1);
      const float* bp = xrow + t2 * FIN + 8 * xs;
      xa = *(const f32x4*)bp;
      xb = zero4();
      if (xs != 15) xb = *(const f32x4*)(bp + 4);
    }

    // 3) Load all pre-barrier A-fragments (h0 prev, x cur, h1 prev).
    s16x8 h0h[2], h0l[2], xh[4], xl[4], h1h[2], h1l[2];
#pragma unroll
    for (int c = 0; c < 2; ++c) {
      h0h[c] = *(const s16x8*)&S0H[P][r16][32 * c + 8 * g];
      h0l[c] = *(const s16x8*)&S0L[P][r16][32 * c + 8 * g];
      h1h[c] = *(const s16x8*)&S1H[P][r16][32 * c + 8 * g];
      h1l[c] = *(const s16x8*)&S1L[P][r16][32 * c + 8 * g];
    }
#pragma unroll
    for (int c = 0; c < 4; ++c) {
      xh[c] = *(const s16x8*)&XH[P][r16][32 * c + 8 * g];
      xl[c] = *(const s16x8*)&XL[P][r16][32 * c + 8 * g];
    }

    // 4) Phase A MFMAs + hoisted h1_prev@Whh1^T. Chains <= 4, round-robin.
    f32x4 a0 = {bias0, bias0, bias0, bias0};
    f32x4 a1 = zero4();
    f32x4 a2 = zero4();
    f32x4 a3 = zero4();
    f32x4 a4 = zero4();
    f32x4 a5 = zero4();
    f32x4 b0 = {bias1, bias1, bias1, bias1};
    f32x4 b1 = zero4();

    a0 = MFMA(h0h[0], WH[0][0][0], a0);
    a1 = MFMA(h0h[0], WH[0][0][1], a1);
    a2 = MFMA(h0l[0], WH[0][0][0], a2);
    a3 = MFMA(xh[2], WI[2][0], a3);
    a4 = MFMA(xh[2], WI[2][1], a4);
    a5 = MFMA(xl[2], WI[2][0], a5);
    b0 = MFMA(h1h[0], WH[2][0][0], b0);
    b1 = MFMA(h1l[0], WH[2][0][0], b1);

    a0 = MFMA(h0h[1], WH[0][1][0], a0);
    a1 = MFMA(h0h[1], WH[0][1][1], a1);
    a2 = MFMA(h0l[1], WH[0][1][0], a2);
    a3 = MFMA(xh[3], WI[3][0], a3);
    a4 = MFMA(xh[3], WI[3][1], a4);
    a5 = MFMA(xl[3], WI[3][0], a5);
    b0 = MFMA(h1h[1], WH[2][1][0], b0);
    b1 = MFMA(h1l[1], WH[2][1][0], b1);

    a0 = MFMA(xh[0], WI[0][0], a0);
    a1 = MFMA(xh[0], WI[0][1], a1);
    a2 = MFMA(xl[0], WI[0][0], a2);
    b0 = MFMA(h1h[0], WH[2][0][1], b0);

    a0 = MFMA(xh[1], WI[1][0], a0);
    a1 = MFMA(xh[1], WI[1][1], a1);
    a2 = MFMA(xl[1], WI[1][0], a2);
    b0 = MFMA(h1h[1], WH[2][1][1], b0);

    // 5) h0_new = tanh(sum) -> S0[1-P] as RNE hi/lo (D: row=4g+i, col=col).
#pragma unroll
    for (int i = 0; i < 4; ++i) {
      float h = tanh_f(((a0[i] + a1[i]) + (a2[i] + a3[i])) + (a4[i] + a5[i]));
      __hip_bfloat16 bh = __float2bfloat16(h);
      float rl = h - __bfloat162float(bh);
      __hip_bfloat16 bl = __float2bfloat16(rl);
      S0H[1 - P][4 * g + i][col] = __builtin_bit_cast(unsigned short, bh);
      S0L[1 - P][4 * g + i][col] = __builtin_bit_cast(unsigned short, bl);
    }
    barrier_lds();

    // 6) Phase B tail: h0_new @ Wih1^T (6 MFMAs, chains <= 4).
    f32x4 b2 = zero4();
    f32x4 b3 = zero4();
#pragma unroll
    for (int c = 0; c < 2; ++c) {
      s16x8 ah = *(const s16x8*)&S0H[1 - P][r16][32 * c + 8 * g];
      s16x8 al = *(const s16x8*)&S0L[1 - P][r16][32 * c + 8 * g];
      b2 = MFMA(ah, WH[1][c][0], b2);
      b3 = MFMA(al, WH[1][c][0], b3);
      b2 = MFMA(ah, WH[1][c][1], b2);
    }
#pragma unroll
    for (int i = 0; i < 4; ++i) {
      float h = tanh_f((b0[i] + b1[i]) + (b2[i] + b3[i]));
      __hip_bfloat16 bh = __float2bfloat16(h);
      float rl = h - __bfloat162float(bh);
      __hip_bfloat16 bl = __float2bfloat16(rl);
      S1H[1 - P][4 * g + i][col] = __builtin_bit_cast(unsigned short, bh);
      S1L[1 - P][4 * g + i][col] = __builtin_bit_cast(unsigned short, bl);
    }
    barrier_lds();
  }

  // ---- FC head: out[n] = h1[n] . Wfc + bfc. Final h1 in buffer 0. ----
  if (tid < 64) {
    const int r = tid & 15;
    const int q = tid >> 4;
    float acc = 0.f;
#pragma unroll
    for (int k = 0; k < 16; ++k) {
      int kk = 16 * q + k;
      float hv = __uint_as_float(((u32)S1H[0][r][kk]) << 16) +
                 __uint_as_float(((u32)S1L[0][r][kk]) << 16);
      acc += hv * WFC[kk];
    }
    RED[tid] = acc;
  }
  barrier_lds();
  if (tid < 16) {
    float o = RED[tid] + RED[tid + 16] + RED[tid + 32] + RED[tid + 48] + bfc[0];
    out[n0 + tid] = o;
  }
}

extern "C" void kernel_launch(void* const* d_in, const int* in_sizes, int n_in,
                              void* d_out, int out_size, void* d_ws,
                              size_t ws_size, hipStream_t stream) {
  (void)in_sizes; (void)n_in; (void)d_ws; (void)ws_size; (void)out_size;
  const float* x    = (const float*)d_in[0];
  const float* Wih0 = (const float*)d_in[1];
  const float* Whh0 = (const float*)d_in[2];
  const float* bih0 = (const float*)d_in[3];
  const float* bhh0 = (const float*)d_in[4];
  const float* Wih1 = (const float*)d_in[5];
  const float* Whh1 = (const float*)d_in[6];
  const float* bih1 = (const float*)d_in[7];
  const float* bhh1 = (const float*)d_in[8];
  const float* Wfc  = (const float*)d_in[9];
  const float* bfc  = (const float*)d_in[10];

  rnn2_fused_kernel<<<256, 256, 0, stream>>>(
      x, Wih0, Whh0, bih0, bhh0, Wih1, Whh1, bih1, bhh1, Wfc, bfc,
      (float*)d_out);
}